// Round 1
// baseline (17.418 us; speedup 1.0000x reference)
//
#include <hip/hip_runtime.h>

// Pairwise squared Euclidean distance: out[b][n][m] = ||A[b][n]-B[b][m]||^2
//   = ||a||^2 + ||b||^2 - 2 a.b  -> batched GEMM (K=64) + norm epilogue.
// B=4, N=M=1024, D=64, fp32.

#define B_ 4
#define N_ 1024
#define M_ 1024
#define D_ 64
#define BN 128
#define BM 128

// swizzle: spreads transposed stores / fragment reads across banks.
// sw(k) = ((k>>2)&7)<<2  (bits 2..4, multiple of 4 -> float4 reads stay intact)
__device__ __forceinline__ int swz(int k) { return ((k >> 2) & 7) << 2; }

__global__ __launch_bounds__(256, 1)
void dist2_kernel(const float* __restrict__ A, const float* __restrict__ Bm,
                  float* __restrict__ out) {
  __shared__ float As[D_][BN];   // As[k][n ^ swz(k)] = A[n][k]
  __shared__ float Bs[D_][BM];
  __shared__ float naS[BN];
  __shared__ float nbS[BM];

  const int tid = threadIdx.x;
  const int b  = blockIdx.z;
  const int n0 = blockIdx.y * BN;
  const int m0 = blockIdx.x * BM;

  const float* Ap = A  + ((size_t)b * N_ + n0) * D_;
  const float* Bp = Bm + ((size_t)b * M_ + m0) * D_;

  // ---- stage A tile (BN rows x 64) transposed + swizzled ----
  #pragma unroll
  for (int i = 0; i < (BN * (D_ / 4)) / 256; ++i) {
    int f  = tid + i * 256;
    int n  = f >> 4;           // row in tile
    int k4 = f & 15;           // float4 index along D
    float4 v = *reinterpret_cast<const float4*>(Ap + n * D_ + k4 * 4);
    int k  = k4 << 2;
    int nn = n ^ swz(k);       // swz constant over the 4 consecutive k
    As[k + 0][nn] = v.x; As[k + 1][nn] = v.y;
    As[k + 2][nn] = v.z; As[k + 3][nn] = v.w;
  }
  // ---- stage B tile ----
  #pragma unroll
  for (int i = 0; i < (BM * (D_ / 4)) / 256; ++i) {
    int f  = tid + i * 256;
    int m  = f >> 4;
    int k4 = f & 15;
    float4 v = *reinterpret_cast<const float4*>(Bp + m * D_ + k4 * 4);
    int k  = k4 << 2;
    int mm = m ^ swz(k);
    Bs[k + 0][mm] = v.x; Bs[k + 1][mm] = v.y;
    Bs[k + 2][mm] = v.z; Bs[k + 3][mm] = v.w;
  }
  __syncthreads();

  // ---- row norms (waves 0-1 -> na, waves 2-3 -> nb) ----
  if (tid < BN) {
    float s = 0.f;
    #pragma unroll 8
    for (int k = 0; k < D_; ++k) {
      float v = As[k][tid ^ swz(k)];
      s = fmaf(v, v, s);
    }
    naS[tid] = s;
  } else {
    int m = tid - BN;
    float s = 0.f;
    #pragma unroll 8
    for (int k = 0; k < D_; ++k) {
      float v = Bs[k][m ^ swz(k)];
      s = fmaf(v, v, s);
    }
    nbS[m] = s;
  }
  __syncthreads();

  // ---- 8x8 micro-tile dot products ----
  // rows: {ty*4..+3} U {64+ty*4..+3}; cols: {tx*4..+3} U {64+tx*4..+3}
  // (split keeps every ds_read_b128 at <=2-way bank aliasing)
  const int ty = tid >> 4;
  const int tx = tid & 15;

  float acc[8][8];
  #pragma unroll
  for (int i = 0; i < 8; ++i)
    #pragma unroll
    for (int j = 0; j < 8; ++j) acc[i][j] = 0.f;

  #pragma unroll 4
  for (int k = 0; k < D_; ++k) {
    const int sw = swz(k);
    float4 a0 = *reinterpret_cast<const float4*>(&As[k][(ty * 4) ^ sw]);
    float4 a1 = *reinterpret_cast<const float4*>(&As[k][(64 + ty * 4) ^ sw]);
    float4 b0 = *reinterpret_cast<const float4*>(&Bs[k][(tx * 4) ^ sw]);
    float4 b1 = *reinterpret_cast<const float4*>(&Bs[k][(64 + tx * 4) ^ sw]);
    float av[8] = {a0.x, a0.y, a0.z, a0.w, a1.x, a1.y, a1.z, a1.w};
    float bv[8] = {b0.x, b0.y, b0.z, b0.w, b1.x, b1.y, b1.z, b1.w};
    #pragma unroll
    for (int i = 0; i < 8; ++i)
      #pragma unroll
      for (int j = 0; j < 8; ++j)
        acc[i][j] = fmaf(av[i], bv[j], acc[i][j]);
  }

  // ---- epilogue: na + nb - 2*dot ----
  float4 na0 = *reinterpret_cast<const float4*>(&naS[ty * 4]);
  float4 na1 = *reinterpret_cast<const float4*>(&naS[64 + ty * 4]);
  float4 nb0 = *reinterpret_cast<const float4*>(&nbS[tx * 4]);
  float4 nb1 = *reinterpret_cast<const float4*>(&nbS[64 + tx * 4]);
  float nav[8] = {na0.x, na0.y, na0.z, na0.w, na1.x, na1.y, na1.z, na1.w};
  float nbv[8] = {nb0.x, nb0.y, nb0.z, nb0.w, nb1.x, nb1.y, nb1.z, nb1.w};

  #pragma unroll
  for (int i = 0; i < 8; ++i) {
    int row = n0 + ((i < 4) ? (ty * 4 + i) : (64 + ty * 4 + (i - 4)));
    float* orow = out + ((size_t)b * N_ + row) * M_ + m0;
    float4 r0, r1;
    r0.x = fmaf(-2.f, acc[i][0], nav[i] + nbv[0]);
    r0.y = fmaf(-2.f, acc[i][1], nav[i] + nbv[1]);
    r0.z = fmaf(-2.f, acc[i][2], nav[i] + nbv[2]);
    r0.w = fmaf(-2.f, acc[i][3], nav[i] + nbv[3]);
    r1.x = fmaf(-2.f, acc[i][4], nav[i] + nbv[4]);
    r1.y = fmaf(-2.f, acc[i][5], nav[i] + nbv[5]);
    r1.z = fmaf(-2.f, acc[i][6], nav[i] + nbv[6]);
    r1.w = fmaf(-2.f, acc[i][7], nav[i] + nbv[7]);
    *reinterpret_cast<float4*>(orow + tx * 4)      = r0;
    *reinterpret_cast<float4*>(orow + 64 + tx * 4) = r1;
  }
}

extern "C" void kernel_launch(void* const* d_in, const int* in_sizes, int n_in,
                              void* d_out, int out_size, void* d_ws, size_t ws_size,
                              hipStream_t stream) {
  const float* A  = (const float*)d_in[0];
  const float* Bm = (const float*)d_in[1];
  float* out = (float*)d_out;
  dim3 grid(M_ / BM, N_ / BN, B_);
  dist2_kernel<<<grid, dim3(256), 0, stream>>>(A, Bm, out);
}

// Round 3
// 16.885 us; speedup vs baseline: 1.0315x; 1.0315x over previous
//
#include <hip/hip_runtime.h>

// out[b][n][m] = ||A[b][n]||^2 + ||B[b][m]||^2 - 2*A[b][n].B[b][m]
// Dot-product on f16 MFMA (error << 5.32 threshold), norms in fp32.
// B=4, N=M=1024, D=64, fp32 in/out.  HBM-write-bound target ~3us.

#define B_ 4
#define N_ 1024
#define M_ 1024
#define D_ 64
#define BN 128
#define BM 128

typedef __attribute__((ext_vector_type(8))) __fp16 f16x8;
typedef __attribute__((ext_vector_type(2))) __fp16 f16x2;
typedef __attribute__((ext_vector_type(4))) float f32x4;

union F16x8 {
  f16x8 v;
  f16x2 h[4];
};

// Load 8 consecutive fp32 at p (16B-aligned), convert to f16x8 (RTZ).
__device__ __forceinline__ f16x8 load_frag8(const float* __restrict__ p) {
  float4 v0 = *reinterpret_cast<const float4*>(p);
  float4 v1 = *reinterpret_cast<const float4*>(p + 4);
  F16x8 r;
  r.h[0] = __builtin_amdgcn_cvt_pkrtz(v0.x, v0.y);
  r.h[1] = __builtin_amdgcn_cvt_pkrtz(v0.z, v0.w);
  r.h[2] = __builtin_amdgcn_cvt_pkrtz(v1.x, v1.y);
  r.h[3] = __builtin_amdgcn_cvt_pkrtz(v1.z, v1.w);
  return r.v;
}

__global__ __launch_bounds__(512, 4)
void dist2_mfma(const float* __restrict__ A, const float* __restrict__ Bm,
                float* __restrict__ out) {
  __shared__ float naS[BN];
  __shared__ float nbS[BM];

  const int tid = threadIdx.x;
  const int b  = blockIdx.z;
  const int n0 = blockIdx.y * BN;
  const int m0 = blockIdx.x * BM;

  const float* Ab = A  + (size_t)b * N_ * D_;
  const float* Bb = Bm + (size_t)b * M_ * D_;

  // ---- fp32 row norms (threads 0..255; one row each) ----
  if (tid < BN + BM) {
    const float* p = (tid < BN) ? (Ab + (size_t)(n0 + tid) * D_)
                                : (Bb + (size_t)(m0 + tid - BN) * D_);
    float s = 0.f;
    #pragma unroll
    for (int k4 = 0; k4 < D_ / 4; ++k4) {
      float4 v = *reinterpret_cast<const float4*>(p + k4 * 4);
      s = fmaf(v.x, v.x, s);
      s = fmaf(v.y, v.y, s);
      s = fmaf(v.z, v.z, s);
      s = fmaf(v.w, v.w, s);
    }
    if (tid < BN) naS[tid] = s; else nbS[tid - BN] = s;
  }

  // ---- MFMA dot products: 8 waves, each owns a 64x32 sub-tile ----
  const int wid  = tid >> 6;
  const int lane = tid & 63;
  const int wrow = wid >> 2;     // 0..1  -> row offset wrow*64
  const int wcol = wid & 3;      // 0..3  -> col offset wcol*32
  const int lr    = lane & 15;   // row/col within 16-group
  const int kbase = (lane >> 4) * 8;

  const float* Arow = Ab + (size_t)(n0 + wrow * 64 + lr) * D_;
  const float* Brow = Bb + (size_t)(m0 + wcol * 32 + lr) * D_;

  f32x4 acc[4][2];
  #pragma unroll
  for (int i = 0; i < 4; ++i)
    #pragma unroll
    for (int j = 0; j < 2; ++j) acc[i][j] = (f32x4){0.f, 0.f, 0.f, 0.f};

  #pragma unroll
  for (int ks = 0; ks < 2; ++ks) {
    const int k = ks * 32 + kbase;
    f16x8 af[4], bf[2];
    #pragma unroll
    for (int i = 0; i < 4; ++i) af[i] = load_frag8(Arow + (size_t)i * 16 * D_ + k);
    #pragma unroll
    for (int j = 0; j < 2; ++j) bf[j] = load_frag8(Brow + (size_t)j * 16 * D_ + k);
    #pragma unroll
    for (int i = 0; i < 4; ++i)
      #pragma unroll
      for (int j = 0; j < 2; ++j)
        acc[i][j] = __builtin_amdgcn_mfma_f32_16x16x32_f16(af[i], bf[j], acc[i][j], 0, 0, 0);
  }

  __syncthreads();   // norms visible to all waves

  // ---- epilogue: na + nb - 2*dot ----
  // C/D layout: col = lane&15, row = (lane>>4)*4 + reg  [m89, dtype-indep]
  const int colA  = lane & 15;
  const int rbase = (lane >> 4) * 4;

  #pragma unroll
  for (int i = 0; i < 4; ++i) {
    #pragma unroll
    for (int j = 0; j < 2; ++j) {
      const int   col = wcol * 32 + j * 16 + colA;
      const float nb  = nbS[col];
      #pragma unroll
      for (int q = 0; q < 4; ++q) {
        const int row = wrow * 64 + i * 16 + rbase + q;
        const float na = naS[row];
        out[((size_t)b * N_ + n0 + row) * M_ + m0 + col] =
            fmaf(-2.f, acc[i][j][q], na + nb);
      }
    }
  }
}

extern "C" void kernel_launch(void* const* d_in, const int* in_sizes, int n_in,
                              void* d_out, int out_size, void* d_ws, size_t ws_size,
                              hipStream_t stream) {
  const float* A  = (const float*)d_in[0];
  const float* Bm = (const float*)d_in[1];
  float* out = (float*)d_out;
  dim3 grid(M_ / BM, N_ / BN, B_);
  dist2_mfma<<<grid, dim3(512), 0, stream>>>(A, Bm, out);
}